// Round 1
// baseline (713.134 us; speedup 1.0000x reference)
//
#include <hip/hip_runtime.h>
#include <math.h>

// Problem constants
#define NB 64
#define NN 4096
#define ND 128
#define NS 8
#define NH 256
#define CHUNKS 16            // attn blocks per batch
#define ROWS_PER_CHUNK 256   // NN / CHUNKS

static constexpr float EPSA  = 1e-8f;
static constexpr float LNE   = 1e-5f;
static constexpr float SCALE = 0.08838834764831845f;  // 1/sqrt(128)

// ---- workspace layout (float offsets) ----
#define OFF_SLOTS 0                        // [64][8][128]
#define OFF_QK    65536                    // [64][8][128]  (scale folded in)
#define OFF_WC    131072                   // [384][128]  W_ih @ Wv
#define OFF_M2T   180224                   // [128][128]  M2T[d'][d] = scale*ln_s_w[d]*Sum_e Wq[e,d]Wk[e,d']
#define OFF_QKB   196608                   // [128]       qkb[d'] = scale*Sum_d ln_s_b[d]*M[d][d']
#define OFF_PART  196736                   // [64][16][8][128] partial updates
#define OFF_PCS   1245312                  // [64][16][8]      partial colsums
// total = 1253504 floats = ~4.8 MB

__device__ __forceinline__ float dot4f(float4 a, float4 b) {
    return fmaf(a.x, b.x, fmaf(a.y, b.y, fmaf(a.z, b.z, a.w * b.w)));
}

// ---------------------------------------------------------------------------
// K0: weight folding + slot init.
//   blocks [0,32):    slots = mu + softplus(sigma)*noise
//   blocks [32,224):  WC[g][f] = Sum_e W_ih[g,e] * Wv[e,f]
//   blocks [224,288): M2T + qkb
// ---------------------------------------------------------------------------
__global__ __launch_bounds__(256) void prep_kernel(
    const float* __restrict__ noise, const float* __restrict__ ln_s_w,
    const float* __restrict__ ln_s_b, const float* __restrict__ slot_mu,
    const float* __restrict__ slot_sigma, const float* __restrict__ Wq,
    const float* __restrict__ Wk, const float* __restrict__ Wv,
    const float* __restrict__ W_ih, float* __restrict__ ws)
{
    int bid = blockIdx.x, t = threadIdx.x;
    if (bid < 32) {
        int i0 = (bid * 256 + t) * 8;
        int d0 = i0 & 127;
        float o[8];
#pragma unroll
        for (int j = 0; j < 8; j++) {
            float sg = slot_sigma[d0 + j];
            float sp = fmaxf(sg, 0.f) + log1pf(expf(-fabsf(sg)));  // softplus
            o[j] = fmaf(sp, noise[i0 + j], slot_mu[d0 + j]);
        }
        float4* dst = (float4*)(ws + OFF_SLOTS + i0);
        dst[0] = make_float4(o[0], o[1], o[2], o[3]);
        dst[1] = make_float4(o[4], o[5], o[6], o[7]);
    } else if (bid < 224) {
        int g = (bid - 32) * 2 + (t >> 7);
        int f = t & 127;
        const float* wih = W_ih + g * ND;
        float acc = 0.f;
        for (int e = 0; e < ND; e++) acc = fmaf(wih[e], Wv[e * ND + f], acc);
        ws[OFF_WC + g * ND + f] = acc;
    } else {
        int dp = (bid - 224) * 2 + (t >> 7);
        int d = t & 127;
        float acc = 0.f;
        for (int e = 0; e < ND; e++) acc = fmaf(Wq[e * ND + d], Wk[e * ND + dp], acc);
        ws[OFF_M2T + dp * ND + d] = SCALE * ln_s_w[d] * acc;
        float c = ln_s_b[d] * acc;
#pragma unroll
        for (int m = 1; m <= 32; m <<= 1) c += __shfl_xor(c, m, 64);
        __shared__ float red[4];
        if ((t & 63) == 0) red[t >> 6] = c;
        __syncthreads();
        if (t == 0)   ws[OFF_QKB + dp] = SCALE * (red[0] + red[1]);
        if (t == 128) ws[OFF_QKB + dp] = SCALE * (red[2] + red[3]);
    }
}

// ---------------------------------------------------------------------------
// qk for iteration 0: qk[b,s,:] = qkb + LN_raw(slots[b,s,:]) @ M2T
// grid 512 = (b*8+s), 128 threads
// ---------------------------------------------------------------------------
__global__ __launch_bounds__(128) void qk_slots_kernel(float* __restrict__ ws)
{
    int b = blockIdx.x >> 3, s = blockIdx.x & 7, t = threadIdx.x;
    const float* slr = ws + OFF_SLOTS + (b * NS + s) * ND;
    float v = slr[t];
    float s1 = v, s2 = v * v;
#pragma unroll
    for (int m = 1; m <= 32; m <<= 1) { s1 += __shfl_xor(s1, m, 64); s2 += __shfl_xor(s2, m, 64); }
    __shared__ float r4[4];
    __shared__ float lnl[ND];
    if ((t & 63) == 0) { r4[(t >> 6) * 2] = s1; r4[(t >> 6) * 2 + 1] = s2; }
    __syncthreads();
    s1 = r4[0] + r4[2]; s2 = r4[1] + r4[3];
    float mean = s1 * (1.f / 128.f);
    float var = fmaf(-mean, mean, s2 * (1.f / 128.f));
    float tv = var + LNE;
    float rs = rsqrtf(tv); rs = rs * (1.5f - 0.5f * tv * rs * rs);
    lnl[t] = (v - mean) * rs;
    __syncthreads();
    const float4* m4 = (const float4*)(ws + OFF_M2T + t * ND);
    const float4* l4 = (const float4*)lnl;
    float acc = ws[OFF_QKB + t];
#pragma unroll 4
    for (int f = 0; f < 32; f++) acc += dot4f(m4[f], l4[f]);
    ws[OFF_QK + (b * NS + s) * ND + t] = acc;
}

// ---------------------------------------------------------------------------
// Main fused pass: LN(inputs) -> dots vs qk -> softmax over 8 -> accumulate
// colsum[s] and raw[s][e] = Sum_n p[n,s]*x[n,e].  Writes per-block partials.
// grid = 64*16, block = 256 (4 waves). Wave handles 4 rows at a time:
// 16 lanes/row, 8 cols/lane.
// ---------------------------------------------------------------------------
__global__ __launch_bounds__(256) void attn_kernel(
    const float* __restrict__ inp, const float* __restrict__ lnw,
    const float* __restrict__ lnb, float* __restrict__ ws)
{
    __shared__ float qk_lds[NS * ND];
    __shared__ float red_lds[4][NS][ND];
    __shared__ float cs_lds[4][NS];
    int t = threadIdx.x;
    int b = blockIdx.x >> 4, chunk = blockIdx.x & 15;
    int w = t >> 6, lane = t & 63;
    int rg = lane >> 4, colg = lane & 15;

    {   // stage this batch's qk (1024 floats)
        const float4* src = (const float4*)(ws + OFF_QK + b * NS * ND);
        ((float4*)qk_lds)[t] = src[t];
    }
    float wv[8], bv[8];
    {
        const float4* w4 = (const float4*)(lnw + colg * 8);
        const float4* b4 = (const float4*)(lnb + colg * 8);
        float4 wa = w4[0], wb = w4[1], ba = b4[0], bb = b4[1];
        wv[0]=wa.x; wv[1]=wa.y; wv[2]=wa.z; wv[3]=wa.w; wv[4]=wb.x; wv[5]=wb.y; wv[6]=wb.z; wv[7]=wb.w;
        bv[0]=ba.x; bv[1]=ba.y; bv[2]=ba.z; bv[3]=ba.w; bv[4]=bb.x; bv[5]=bb.y; bv[6]=bb.z; bv[7]=bb.w;
    }
    float acc[NS][8];
    float cs[NS];
#pragma unroll
    for (int si = 0; si < NS; si++) {
        cs[si] = 0.f;
#pragma unroll
        for (int j = 0; j < 8; j++) acc[si][j] = 0.f;
    }
    __syncthreads();

    const float* base = inp + ((size_t)b * NN + chunk * ROWS_PER_CHUNK + w * 64 + rg) * ND + colg * 8;
    for (int q = 0; q < 16; q++) {
        const float* rp = base + q * 4 * ND;
        float4 a0 = *(const float4*)rp;
        float4 a1 = *(const float4*)(rp + 4);
        float x[8] = {a0.x, a0.y, a0.z, a0.w, a1.x, a1.y, a1.z, a1.w};
        float s1 = 0.f, s2 = 0.f;
#pragma unroll
        for (int j = 0; j < 8; j++) { s1 += x[j]; s2 = fmaf(x[j], x[j], s2); }
#pragma unroll
        for (int m = 1; m <= 8; m <<= 1) { s1 += __shfl_xor(s1, m, 64); s2 += __shfl_xor(s2, m, 64); }
        float mean = s1 * (1.f / 128.f);
        float var = fmaf(-mean, mean, s2 * (1.f / 128.f));
        float tv = var + LNE;
        float rs = rsqrtf(tv); rs = rs * (1.5f - 0.5f * tv * rs * rs);
#pragma unroll
        for (int j = 0; j < 8; j++) x[j] = fmaf((x[j] - mean) * rs, wv[j], bv[j]);

        float pd[NS];
#pragma unroll
        for (int si = 0; si < NS; si++) {
            const float4* q4 = (const float4*)(qk_lds + si * ND + colg * 8);
            float4 q0 = q4[0], q1 = q4[1];
            float p = x[0] * q0.x;
            p = fmaf(x[1], q0.y, p); p = fmaf(x[2], q0.z, p); p = fmaf(x[3], q0.w, p);
            p = fmaf(x[4], q1.x, p); p = fmaf(x[5], q1.y, p); p = fmaf(x[6], q1.z, p);
            p = fmaf(x[7], q1.w, p);
            pd[si] = p;
        }
#pragma unroll
        for (int m = 1; m <= 8; m <<= 1) {
#pragma unroll
            for (int si = 0; si < NS; si++) pd[si] += __shfl_xor(pd[si], m, 64);
        }
        float mx = fmaxf(fmaxf(fmaxf(pd[0], pd[1]), fmaxf(pd[2], pd[3])),
                         fmaxf(fmaxf(pd[4], pd[5]), fmaxf(pd[6], pd[7])));
        float ev[NS]; float es = 0.f;
#pragma unroll
        for (int si = 0; si < NS; si++) { ev[si] = __expf(pd[si] - mx); es += ev[si]; }
        float inv = 1.0f / es;
#pragma unroll
        for (int si = 0; si < NS; si++) {
            float p = ev[si] * inv;
            cs[si] += p;
#pragma unroll
            for (int j = 0; j < 8; j++) acc[si][j] = fmaf(p, x[j], acc[si][j]);
        }
    }
    // reduce across the 4 row-groups within the wave
#pragma unroll
    for (int m = 16; m <= 32; m <<= 1) {
#pragma unroll
        for (int si = 0; si < NS; si++) {
            cs[si] += __shfl_xor(cs[si], m, 64);
#pragma unroll
            for (int j = 0; j < 8; j++) acc[si][j] += __shfl_xor(acc[si][j], m, 64);
        }
    }
    if (lane < 16) {
#pragma unroll
        for (int si = 0; si < NS; si++) {
            *(float4*)&red_lds[w][si][lane * 8]     = make_float4(acc[si][0], acc[si][1], acc[si][2], acc[si][3]);
            *(float4*)&red_lds[w][si][lane * 8 + 4] = make_float4(acc[si][4], acc[si][5], acc[si][6], acc[si][7]);
        }
    }
    if (lane == 0) {
#pragma unroll
        for (int si = 0; si < NS; si++) cs_lds[w][si] = cs[si];
    }
    __syncthreads();
    float* pout = ws + OFF_PART + (size_t)(b * CHUNKS + chunk) * (NS * ND);
#pragma unroll
    for (int k = 0; k < 4; k++) {
        int o = t + k * 256;
        pout[o] = red_lds[0][0][o] + red_lds[1][0][o] + red_lds[2][0][o] + red_lds[3][0][o];
    }
    if (t < NS) {
        ws[OFF_PCS + (b * CHUNKS + chunk) * NS + t] =
            cs_lds[0][t] + cs_lds[1][t] + cs_lds[2][t] + cs_lds[3][t];
    }
}

// ---------------------------------------------------------------------------
// Fused: partial-reduce -> normalize (+EPS terms) -> GRU -> new slots ->
//   (!LAST) qk for next iteration | (LAST) MLP -> final output
// grid 64 (one per batch), 512 threads.
// ---------------------------------------------------------------------------
template <int LAST>
__global__ __launch_bounds__(512) void gru_kernel(
    const float* __restrict__ W_hh, const float* __restrict__ b_ih,
    const float* __restrict__ b_hh, const float* __restrict__ W1,
    const float* __restrict__ b1, const float* __restrict__ W2,
    const float* __restrict__ b2, const float* __restrict__ ln_m_w,
    const float* __restrict__ ln_m_b, float* __restrict__ ws,
    float* __restrict__ out)
{
    __shared__ float sh_nr[NS * ND];   // raw updates -> normalized -> new slots
    __shared__ float sh_sp[NS * ND];   // slots_prev
    __shared__ float sh_cs[NS];
    __shared__ float sh_sx[ND];
    __shared__ float sh_gi[NS * 384];  // reused as h[8][256] in LAST path
    __shared__ float sh_gh[NS * 384];
    __shared__ float sh_ln[NS * ND];
    int b = blockIdx.x, t = threadIdx.x;

    const float* part = ws + OFF_PART + (size_t)b * CHUNKS * NS * ND;
    float r0 = 0.f, r1 = 0.f;
#pragma unroll
    for (int p = 0; p < CHUNKS; p++) {
        r0 += part[p * (NS * ND) + t];
        r1 += part[p * (NS * ND) + t + 512];
    }
    sh_nr[t] = r0; sh_nr[t + 512] = r1;
    if (t < NS) {
        const float* pcs = ws + OFF_PCS + b * CHUNKS * NS;
        float c = 0.f;
#pragma unroll
        for (int p = 0; p < CHUNKS; p++) c += pcs[p * NS + t];
        sh_cs[t] = c + (float)NN * EPSA;
    }
    const float* slr = ws + OFF_SLOTS + b * (NS * ND);
    sh_sp[t] = slr[t]; sh_sp[t + 512] = slr[t + 512];
    __syncthreads();
    if (t < ND) {   // Sx[e] = Sum_s raw[s][e]  (== Sum_n x[n][e] since softmax sums to 1)
        float a = 0.f;
#pragma unroll
        for (int si = 0; si < NS; si++) a += sh_nr[si * ND + t];
        sh_sx[t] = a;
    }
    __syncthreads();
    {
        int e0 = t & 127, s0 = t >> 7;
        int o1 = t + 512; int e1 = o1 & 127, s1_ = o1 >> 7;
        sh_nr[t]  = fmaf(EPSA, sh_sx[e0], r0) / sh_cs[s0];
        sh_nr[o1] = fmaf(EPSA, sh_sx[e1], r1) / sh_cs[s1_];
    }
    __syncthreads();
    {   // gi = nr @ WC^T + b_ih ; gh = sp @ W_hh^T + b_hh
        int s_ = t >> 6, e0 = t & 63;
        const float4* nr4 = (const float4*)(sh_nr + s_ * ND);
        const float4* sp4 = (const float4*)(sh_sp + s_ * ND);
#pragma unroll 1
        for (int k = 0; k < 6; k++) {
            int e3 = e0 + k * 64;
            const float4* wc4 = (const float4*)(ws + OFF_WC + e3 * ND);
            const float4* wh4 = (const float4*)(W_hh + e3 * ND);
            float ai = b_ih[e3], ah = b_hh[e3];
#pragma unroll 4
            for (int f = 0; f < 32; f++) {
                ai += dot4f(nr4[f], wc4[f]);
                ah += dot4f(sp4[f], wh4[f]);
            }
            sh_gi[s_ * 384 + e3] = ai;
            sh_gh[s_ * 384 + e3] = ah;
        }
    }
    __syncthreads();
#pragma unroll
    for (int k = 0; k < 2; k++) {   // gates -> new slots (into sh_nr)
        int o = t + k * 512; int si = o >> 7, d = o & 127;
        float gir = sh_gi[si * 384 + d],       ghr = sh_gh[si * 384 + d];
        float giz = sh_gi[si * 384 + 128 + d], ghz = sh_gh[si * 384 + 128 + d];
        float gin = sh_gi[si * 384 + 256 + d], ghn = sh_gh[si * 384 + 256 + d];
        float r = 1.f / (1.f + expf(-(gir + ghr)));
        float z = 1.f / (1.f + expf(-(giz + ghz)));
        float nn_ = tanhf(fmaf(r, ghn, gin));
        float ns = fmaf(z, sh_sp[o] - nn_, nn_);   // (1-z)*nn + z*sp
        sh_nr[o] = ns;
        if (!LAST) ws[OFF_SLOTS + b * (NS * ND) + o] = ns;
    }
    __syncthreads();
    {   // LN of new slots: wave w handles slot w (64 lanes x 2 cols)
        int wid = t >> 6, l_ = t & 63;
        float v0 = sh_nr[wid * ND + 2 * l_], v1 = sh_nr[wid * ND + 2 * l_ + 1];
        float s1 = v0 + v1, s2 = fmaf(v0, v0, v1 * v1);
#pragma unroll
        for (int m = 1; m <= 32; m <<= 1) { s1 += __shfl_xor(s1, m, 64); s2 += __shfl_xor(s2, m, 64); }
        float mean = s1 * (1.f / 128.f);
        float var = fmaf(-mean, mean, s2 * (1.f / 128.f));
        float tv = var + LNE;
        float rs = rsqrtf(tv); rs = rs * (1.5f - 0.5f * tv * rs * rs);
        float x0 = (v0 - mean) * rs, x1 = (v1 - mean) * rs;
        if (LAST) {
            x0 = fmaf(x0, ln_m_w[2 * l_],     ln_m_b[2 * l_]);
            x1 = fmaf(x1, ln_m_w[2 * l_ + 1], ln_m_b[2 * l_ + 1]);
        }
        sh_ln[wid * ND + 2 * l_]     = x0;
        sh_ln[wid * ND + 2 * l_ + 1] = x1;
    }
    __syncthreads();
    if (!LAST) {   // qk = qkb + ln @ M2T^T (scale & ln_s affine folded)
#pragma unroll
        for (int k = 0; k < 2; k++) {
            int o = t + k * 512; int si = o >> 7, dp = o & 127;
            const float4* m4 = (const float4*)(ws + OFF_M2T + dp * ND);
            const float4* l4 = (const float4*)(sh_ln + si * ND);
            float acc = ws[OFF_QKB + dp];
#pragma unroll 4
            for (int f = 0; f < 32; f++) acc += dot4f(m4[f], l4[f]);
            ws[OFF_QK + b * (NS * ND) + o] = acc;
        }
    } else {       // MLP: h = relu(ln @ W1^T + b1); out = ns + h @ W2^T + b2
#pragma unroll 1
        for (int k = 0; k < 4; k++) {
            int o = t + k * 512; int si = o >> 8, hh = o & 255;
            const float4* w14 = (const float4*)(W1 + hh * ND);
            const float4* l4 = (const float4*)(sh_ln + si * ND);
            float a = b1[hh];
#pragma unroll 4
            for (int f = 0; f < 32; f++) a += dot4f(w14[f], l4[f]);
            sh_gi[si * NH + hh] = fmaxf(a, 0.f);
        }
        __syncthreads();
#pragma unroll 1
        for (int k = 0; k < 2; k++) {
            int o = t + k * 512; int si = o >> 7, d = o & 127;
            const float4* w24 = (const float4*)(W2 + d * NH);
            const float4* h4 = (const float4*)(sh_gi + si * NH);
            float a = b2[d] + sh_nr[o];
#pragma unroll 4
            for (int f = 0; f < 64; f++) a += dot4f(w24[f], h4[f]);
            out[(size_t)b * (NS * ND) + o] = a;
        }
    }
}

// ---------------------------------------------------------------------------
extern "C" void kernel_launch(void* const* d_in, const int* in_sizes, int n_in,
                              void* d_out, int out_size, void* d_ws, size_t ws_size,
                              hipStream_t stream) {
    (void)in_sizes; (void)n_in; (void)out_size; (void)ws_size;
    const float* inputs     = (const float*)d_in[0];
    const float* noise      = (const float*)d_in[1];
    const float* ln_in_w    = (const float*)d_in[2];
    const float* ln_in_b    = (const float*)d_in[3];
    const float* ln_s_w     = (const float*)d_in[4];
    const float* ln_s_b     = (const float*)d_in[5];
    const float* ln_m_w     = (const float*)d_in[6];
    const float* ln_m_b     = (const float*)d_in[7];
    const float* slot_mu    = (const float*)d_in[8];
    const float* slot_sigma = (const float*)d_in[9];
    const float* Wq         = (const float*)d_in[10];
    const float* Wk         = (const float*)d_in[11];
    const float* Wv         = (const float*)d_in[12];
    const float* W_ih       = (const float*)d_in[13];
    const float* W_hh       = (const float*)d_in[14];
    const float* b_ih       = (const float*)d_in[15];
    const float* b_hh       = (const float*)d_in[16];
    const float* W1         = (const float*)d_in[17];
    const float* b1         = (const float*)d_in[18];
    const float* W2         = (const float*)d_in[19];
    const float* b2         = (const float*)d_in[20];
    float* ws  = (float*)d_ws;
    float* out = (float*)d_out;

    hipLaunchKernelGGL(prep_kernel, dim3(288), dim3(256), 0, stream,
                       noise, ln_s_w, ln_s_b, slot_mu, slot_sigma, Wq, Wk, Wv, W_ih, ws);
    hipLaunchKernelGGL(qk_slots_kernel, dim3(512), dim3(128), 0, stream, ws);
    for (int it = 0; it < 3; ++it) {
        hipLaunchKernelGGL(attn_kernel, dim3(NB * CHUNKS), dim3(256), 0, stream,
                           inputs, ln_in_w, ln_in_b, ws);
        if (it < 2) {
            hipLaunchKernelGGL((gru_kernel<0>), dim3(NB), dim3(512), 0, stream,
                               W_hh, b_ih, b_hh, W1, b1, W2, b2, ln_m_w, ln_m_b, ws, out);
        } else {
            hipLaunchKernelGGL((gru_kernel<1>), dim3(NB), dim3(512), 0, stream,
                               W_hh, b_ih, b_hh, W1, b1, W2, b2, ln_m_w, ln_m_b, ws, out);
        }
    }
}

// Round 2
// 484.766 us; speedup vs baseline: 1.4711x; 1.4711x over previous
//
#include <hip/hip_runtime.h>
#include <math.h>

// Problem constants
#define NB 64
#define NN 4096
#define ND 128
#define NS 8
#define NH 256
#define CHUNKS 16            // attn blocks per batch
#define ROWS_PER_CHUNK 256   // NN / CHUNKS

static constexpr float EPSA  = 1e-8f;
static constexpr float LNE   = 1e-5f;
static constexpr float SCALE = 0.08838834764831845f;  // 1/sqrt(128)

// ---- workspace layout (float offsets) ----
#define OFF_SLOTS 0                        // [64][8][128]
#define OFF_QK    65536                    // [64][8][128]  (scale folded in)
#define OFF_WC    131072                   // [384][128]  W_ih @ Wv
#define OFF_M2T   180224                   // [128][128]  M2T[d'][d] = scale*ln_s_w[d]*Sum_e Wq[e,d]Wk[e,d']
#define OFF_QKB   196608                   // [128]       qkb[d'] = scale*Sum_d ln_s_b[d]*M[d][d']
#define OFF_PART  196736                   // [64][16][8][128] partial updates
#define OFF_PCS   1245312                  // [64][16][8]      partial colsums

__device__ __forceinline__ float dot4f(float4 a, float4 b) {
    return fmaf(a.x, b.x, fmaf(a.y, b.y, fmaf(a.z, b.z, a.w * b.w)));
}

// ---------------------------------------------------------------------------
// K0: weight folding + slot init.  (unchanged — already coalesced)
// ---------------------------------------------------------------------------
__global__ __launch_bounds__(256) void prep_kernel(
    const float* __restrict__ noise, const float* __restrict__ ln_s_w,
    const float* __restrict__ ln_s_b, const float* __restrict__ slot_mu,
    const float* __restrict__ slot_sigma, const float* __restrict__ Wq,
    const float* __restrict__ Wk, const float* __restrict__ Wv,
    const float* __restrict__ W_ih, float* __restrict__ ws)
{
    int bid = blockIdx.x, t = threadIdx.x;
    if (bid < 32) {
        int i0 = (bid * 256 + t) * 8;
        int d0 = i0 & 127;
        float o[8];
#pragma unroll
        for (int j = 0; j < 8; j++) {
            float sg = slot_sigma[d0 + j];
            float sp = fmaxf(sg, 0.f) + log1pf(expf(-fabsf(sg)));  // softplus
            o[j] = fmaf(sp, noise[i0 + j], slot_mu[d0 + j]);
        }
        float4* dst = (float4*)(ws + OFF_SLOTS + i0);
        dst[0] = make_float4(o[0], o[1], o[2], o[3]);
        dst[1] = make_float4(o[4], o[5], o[6], o[7]);
    } else if (bid < 224) {
        int g = (bid - 32) * 2 + (t >> 7);
        int f = t & 127;
        const float* wih = W_ih + g * ND;
        float acc = 0.f;
        for (int e = 0; e < ND; e++) acc = fmaf(wih[e], Wv[e * ND + f], acc);
        ws[OFF_WC + g * ND + f] = acc;
    } else {
        int dp = (bid - 224) * 2 + (t >> 7);
        int d = t & 127;
        float acc = 0.f;
        for (int e = 0; e < ND; e++) acc = fmaf(Wq[e * ND + d], Wk[e * ND + dp], acc);
        ws[OFF_M2T + dp * ND + d] = SCALE * ln_s_w[d] * acc;
        float c = ln_s_b[d] * acc;
#pragma unroll
        for (int m = 1; m <= 32; m <<= 1) c += __shfl_xor(c, m, 64);
        __shared__ float red[4];
        if ((t & 63) == 0) red[t >> 6] = c;
        __syncthreads();
        if (t == 0)   ws[OFF_QKB + dp] = SCALE * (red[0] + red[1]);
        if (t == 128) ws[OFF_QKB + dp] = SCALE * (red[2] + red[3]);
    }
}

// ---------------------------------------------------------------------------
// qk for iteration 0 — coalesced rewrite.  grid 64 (per batch), 512 threads.
// ---------------------------------------------------------------------------
__global__ __launch_bounds__(512) void qk0_kernel(float* __restrict__ ws)
{
    __shared__ float sh_s[NS * ND];
    __shared__ float sh_ln[NS * ND];
    int b = blockIdx.x, t = threadIdx.x;
    sh_s[t]       = ws[OFF_SLOTS + b * NS * ND + t];
    sh_s[t + 512] = ws[OFF_SLOTS + b * NS * ND + t + 512];
    __syncthreads();
    {   // LN(raw): wave w handles slot w, 64 lanes x 2 cols
        int wid = t >> 6, l = t & 63;
        float v0 = sh_s[wid * ND + 2 * l], v1 = sh_s[wid * ND + 2 * l + 1];
        float s1 = v0 + v1, s2 = fmaf(v0, v0, v1 * v1);
#pragma unroll
        for (int m = 1; m <= 32; m <<= 1) { s1 += __shfl_xor(s1, m, 64); s2 += __shfl_xor(s2, m, 64); }
        float mean = s1 * (1.f / 128.f);
        float var = fmaf(-mean, mean, s2 * (1.f / 128.f));
        float tv = var + LNE;
        float rs = rsqrtf(tv); rs = rs * (1.5f - 0.5f * tv * rs * rs);
        sh_ln[wid * ND + 2 * l]     = (v0 - mean) * rs;
        sh_ln[wid * ND + 2 * l + 1] = (v1 - mean) * rs;
    }
    __syncthreads();
    {   // qk[s][dp] = qkb[dp] + ln[s] . M2T[dp]   (8 lanes per output)
        int g = t >> 3, c = t & 7, s = g >> 3, dp0 = g & 7;
        const float4* lp = (const float4*)(sh_ln + s * ND + c * 16);
        float4 l0 = lp[0], l1 = lp[1], l2 = lp[2], l3 = lp[3];
#pragma unroll 2
        for (int j = 0; j < 16; j++) {
            int dp = dp0 + 8 * j;
            const float4* m4 = (const float4*)(ws + OFF_M2T + dp * ND + c * 16);
            float a = dot4f(m4[0], l0) + dot4f(m4[1], l1) + dot4f(m4[2], l2) + dot4f(m4[3], l3);
            a += __shfl_xor(a, 1); a += __shfl_xor(a, 2); a += __shfl_xor(a, 4);
            if (c == 0) ws[OFF_QK + b * NS * ND + s * ND + dp] = a + ws[OFF_QKB + dp];
        }
    }
}

// ---------------------------------------------------------------------------
// Main fused pass (unchanged structure; +unroll2, +fast rcp)
// ---------------------------------------------------------------------------
__global__ __launch_bounds__(256) void attn_kernel(
    const float* __restrict__ inp, const float* __restrict__ lnw,
    const float* __restrict__ lnb, float* __restrict__ ws)
{
    __shared__ float qk_lds[NS * ND];
    __shared__ float red_lds[4][NS][ND];
    __shared__ float cs_lds[4][NS];
    int t = threadIdx.x;
    int b = blockIdx.x >> 4, chunk = blockIdx.x & 15;
    int w = t >> 6, lane = t & 63;
    int rg = lane >> 4, colg = lane & 15;

    {
        const float4* src = (const float4*)(ws + OFF_QK + b * NS * ND);
        ((float4*)qk_lds)[t] = src[t];
    }
    float wv[8], bv[8];
    {
        const float4* w4 = (const float4*)(lnw + colg * 8);
        const float4* b4 = (const float4*)(lnb + colg * 8);
        float4 wa = w4[0], wb = w4[1], ba = b4[0], bb = b4[1];
        wv[0]=wa.x; wv[1]=wa.y; wv[2]=wa.z; wv[3]=wa.w; wv[4]=wb.x; wv[5]=wb.y; wv[6]=wb.z; wv[7]=wb.w;
        bv[0]=ba.x; bv[1]=ba.y; bv[2]=ba.z; bv[3]=ba.w; bv[4]=bb.x; bv[5]=bb.y; bv[6]=bb.z; bv[7]=bb.w;
    }
    float acc[NS][8];
    float cs[NS];
#pragma unroll
    for (int si = 0; si < NS; si++) {
        cs[si] = 0.f;
#pragma unroll
        for (int j = 0; j < 8; j++) acc[si][j] = 0.f;
    }
    __syncthreads();

    const float* base = inp + ((size_t)b * NN + chunk * ROWS_PER_CHUNK + w * 64 + rg) * ND + colg * 8;
#pragma unroll 2
    for (int q = 0; q < 16; q++) {
        const float* rp = base + q * 4 * ND;
        float4 a0 = *(const float4*)rp;
        float4 a1 = *(const float4*)(rp + 4);
        float x[8] = {a0.x, a0.y, a0.z, a0.w, a1.x, a1.y, a1.z, a1.w};
        float s1 = 0.f, s2 = 0.f;
#pragma unroll
        for (int j = 0; j < 8; j++) { s1 += x[j]; s2 = fmaf(x[j], x[j], s2); }
#pragma unroll
        for (int m = 1; m <= 8; m <<= 1) { s1 += __shfl_xor(s1, m, 64); s2 += __shfl_xor(s2, m, 64); }
        float mean = s1 * (1.f / 128.f);
        float var = fmaf(-mean, mean, s2 * (1.f / 128.f));
        float tv = var + LNE;
        float rs = rsqrtf(tv); rs = rs * (1.5f - 0.5f * tv * rs * rs);
#pragma unroll
        for (int j = 0; j < 8; j++) x[j] = fmaf((x[j] - mean) * rs, wv[j], bv[j]);

        float pd[NS];
#pragma unroll
        for (int si = 0; si < NS; si++) {
            const float4* q4 = (const float4*)(qk_lds + si * ND + colg * 8);
            float4 q0 = q4[0], q1 = q4[1];
            float p = x[0] * q0.x;
            p = fmaf(x[1], q0.y, p); p = fmaf(x[2], q0.z, p); p = fmaf(x[3], q0.w, p);
            p = fmaf(x[4], q1.x, p); p = fmaf(x[5], q1.y, p); p = fmaf(x[6], q1.z, p);
            p = fmaf(x[7], q1.w, p);
            pd[si] = p;
        }
#pragma unroll
        for (int m = 1; m <= 8; m <<= 1) {
#pragma unroll
            for (int si = 0; si < NS; si++) pd[si] += __shfl_xor(pd[si], m, 64);
        }
        float mx = fmaxf(fmaxf(fmaxf(pd[0], pd[1]), fmaxf(pd[2], pd[3])),
                         fmaxf(fmaxf(pd[4], pd[5]), fmaxf(pd[6], pd[7])));
        float ev[NS]; float es = 0.f;
#pragma unroll
        for (int si = 0; si < NS; si++) { ev[si] = __expf(pd[si] - mx); es += ev[si]; }
        float r0 = __builtin_amdgcn_rcpf(es);
        float inv = r0 * (2.0f - es * r0);   // 1 NR step
#pragma unroll
        for (int si = 0; si < NS; si++) {
            float p = ev[si] * inv;
            cs[si] += p;
#pragma unroll
            for (int j = 0; j < 8; j++) acc[si][j] = fmaf(p, x[j], acc[si][j]);
        }
    }
#pragma unroll
    for (int m = 16; m <= 32; m <<= 1) {
#pragma unroll
        for (int si = 0; si < NS; si++) {
            cs[si] += __shfl_xor(cs[si], m, 64);
#pragma unroll
            for (int j = 0; j < 8; j++) acc[si][j] += __shfl_xor(acc[si][j], m, 64);
        }
    }
    if (lane < 16) {
#pragma unroll
        for (int si = 0; si < NS; si++) {
            *(float4*)&red_lds[w][si][lane * 8]     = make_float4(acc[si][0], acc[si][1], acc[si][2], acc[si][3]);
            *(float4*)&red_lds[w][si][lane * 8 + 4] = make_float4(acc[si][4], acc[si][5], acc[si][6], acc[si][7]);
        }
    }
    if (lane == 0) {
#pragma unroll
        for (int si = 0; si < NS; si++) cs_lds[w][si] = cs[si];
    }
    __syncthreads();
    float* pout = ws + OFF_PART + (size_t)(b * CHUNKS + chunk) * (NS * ND);
#pragma unroll
    for (int k = 0; k < 4; k++) {
        int o = t + k * 256;
        pout[o] = red_lds[0][0][o] + red_lds[1][0][o] + red_lds[2][0][o] + red_lds[3][0][o];
    }
    if (t < NS) {
        ws[OFF_PCS + (b * CHUNKS + chunk) * NS + t] =
            cs_lds[0][t] + cs_lds[1][t] + cs_lds[2][t] + cs_lds[3][t];
    }
}

// ---------------------------------------------------------------------------
// GRU + next-qk / final-MLP.  Coalesced rewrite, 2 blocks per batch
// (4 slots each).  grid 128, 512 threads.
// ---------------------------------------------------------------------------
template <int LAST>
__global__ __launch_bounds__(512) void gru_kernel(
    const float* __restrict__ W_hh, const float* __restrict__ b_ih,
    const float* __restrict__ b_hh, const float* __restrict__ W1,
    const float* __restrict__ b1, const float* __restrict__ W2,
    const float* __restrict__ b2, const float* __restrict__ ln_m_w,
    const float* __restrict__ ln_m_b, float* __restrict__ ws,
    float* __restrict__ out)
{
    __shared__ float sh_nr[4 * ND];    // raw -> normalized updates -> new slots
    __shared__ float sh_sp[4 * ND];    // slots_prev (this half)
    __shared__ float sh_tmp[512];
    __shared__ float sh_sx[ND];
    __shared__ float sh_cs[4];
    __shared__ float sh_gi[4 * 384];   // reused as h[4][256] in LAST path
    __shared__ float sh_gh[4 * 384];
    __shared__ float sh_ln[4 * ND];
    int b = blockIdx.x >> 1, sh2 = blockIdx.x & 1;
    int t = threadIdx.x;

    const float* partf = ws + OFF_PART + (size_t)b * CHUNKS * NS * ND;
    // ---- A: partial reduce (this half's 4 slots), Sx over all 8 slots, colsums
    {
        float r = 0.f;
#pragma unroll
        for (int p = 0; p < CHUNKS; p++) r += partf[p * 1024 + sh2 * 512 + t];
        sh_nr[t] = r;
    }
    {
        int e = t & 127, q = t >> 7;
        float a = 0.f;
#pragma unroll
        for (int p = q * 4; p < q * 4 + 4; p++)
#pragma unroll
            for (int s = 0; s < 8; s++) a += partf[p * 1024 + s * 128 + e];
        sh_tmp[t] = a;
    }
    if (t < 4) {
        const float* pcs = ws + OFF_PCS + b * CHUNKS * NS;
        float c = 0.f;
#pragma unroll
        for (int p = 0; p < CHUNKS; p++) c += pcs[p * NS + sh2 * 4 + t];
        sh_cs[t] = c + (float)NN * EPSA;
    }
    sh_sp[t] = ws[OFF_SLOTS + b * NS * ND + sh2 * 512 + t];
    __syncthreads();
    if (t < ND) sh_sx[t] = sh_tmp[t] + sh_tmp[t + 128] + sh_tmp[t + 256] + sh_tmp[t + 384];
    __syncthreads();
    // ---- B: normalize
    sh_nr[t] = fmaf(EPSA, sh_sx[t & 127], sh_nr[t]) / sh_cs[t >> 7];
    __syncthreads();
    // ---- C: gi = nr@WC^T + b_ih, gh = sp@W_hh^T + b_hh (8 lanes per output)
    int g = t >> 3, c = t & 7;
    int sl = g >> 4, g3 = g & 15;      // local slot 0..3, row phase 0..15
    {
        const float4* np = (const float4*)(sh_nr + sl * ND + c * 16);
        const float4* pp = (const float4*)(sh_sp + sl * ND + c * 16);
        float4 n0 = np[0], n1 = np[1], n2 = np[2], n3 = np[3];
        float4 p0 = pp[0], p1 = pp[1], p2 = pp[2], p3 = pp[3];
#pragma unroll 2
        for (int j = 0; j < 24; j++) {
            int e3 = g3 + 16 * j;
            const float4* wc4 = (const float4*)(ws + OFF_WC + e3 * ND + c * 16);
            const float4* wh4 = (const float4*)(W_hh + e3 * ND + c * 16);
            float ai = dot4f(wc4[0], n0) + dot4f(wc4[1], n1) + dot4f(wc4[2], n2) + dot4f(wc4[3], n3);
            float ah = dot4f(wh4[0], p0) + dot4f(wh4[1], p1) + dot4f(wh4[2], p2) + dot4f(wh4[3], p3);
            ai += __shfl_xor(ai, 1); ah += __shfl_xor(ah, 1);
            ai += __shfl_xor(ai, 2); ah += __shfl_xor(ah, 2);
            ai += __shfl_xor(ai, 4); ah += __shfl_xor(ah, 4);
            if (c == 0) {
                sh_gi[sl * 384 + e3] = ai + b_ih[e3];
                sh_gh[sl * 384 + e3] = ah + b_hh[e3];
            }
        }
    }
    __syncthreads();
    // ---- D: gates -> new slots
    {
        int si = t >> 7, d = t & 127;
        float gir = sh_gi[si * 384 + d],       ghr = sh_gh[si * 384 + d];
        float giz = sh_gi[si * 384 + 128 + d], ghz = sh_gh[si * 384 + 128 + d];
        float gin = sh_gi[si * 384 + 256 + d], ghn = sh_gh[si * 384 + 256 + d];
        float rr = 1.f / (1.f + expf(-(gir + ghr)));
        float z  = 1.f / (1.f + expf(-(giz + ghz)));
        float nn_ = tanhf(fmaf(rr, ghn, gin));
        float ns = fmaf(z, sh_sp[t] - nn_, nn_);
        sh_nr[t] = ns;
        if (!LAST) ws[OFF_SLOTS + b * NS * ND + sh2 * 512 + t] = ns;
    }
    __syncthreads();
    // ---- E: LN of new slots (waves 0..3, one slot each)
    {
        int wid = t >> 6, l = t & 63;
        if (wid < 4) {
            float v0 = sh_nr[wid * ND + 2 * l], v1 = sh_nr[wid * ND + 2 * l + 1];
            float s1 = v0 + v1, s2 = fmaf(v0, v0, v1 * v1);
#pragma unroll
            for (int m = 1; m <= 32; m <<= 1) { s1 += __shfl_xor(s1, m, 64); s2 += __shfl_xor(s2, m, 64); }
            float mean = s1 * (1.f / 128.f);
            float var = fmaf(-mean, mean, s2 * (1.f / 128.f));
            float tv = var + LNE;
            float rs = rsqrtf(tv); rs = rs * (1.5f - 0.5f * tv * rs * rs);
            float x0 = (v0 - mean) * rs, x1 = (v1 - mean) * rs;
            if (LAST) {
                x0 = fmaf(x0, ln_m_w[2 * l],     ln_m_b[2 * l]);
                x1 = fmaf(x1, ln_m_w[2 * l + 1], ln_m_b[2 * l + 1]);
            }
            sh_ln[wid * ND + 2 * l]     = x0;
            sh_ln[wid * ND + 2 * l + 1] = x1;
        }
    }
    __syncthreads();
    if (!LAST) {   // ---- F: qk for next iteration
        const float4* lp = (const float4*)(sh_ln + sl * ND + c * 16);
        float4 l0 = lp[0], l1 = lp[1], l2 = lp[2], l3 = lp[3];
#pragma unroll 2
        for (int j = 0; j < 8; j++) {
            int dp = g3 + 16 * j;
            const float4* m4 = (const float4*)(ws + OFF_M2T + dp * ND + c * 16);
            float a = dot4f(m4[0], l0) + dot4f(m4[1], l1) + dot4f(m4[2], l2) + dot4f(m4[3], l3);
            a += __shfl_xor(a, 1); a += __shfl_xor(a, 2); a += __shfl_xor(a, 4);
            if (c == 0) ws[OFF_QK + b * NS * ND + (sh2 * 4 + sl) * ND + dp] = a + ws[OFF_QKB + dp];
        }
    } else {       // ---- F: MLP
        const float4* lp = (const float4*)(sh_ln + sl * ND + c * 16);
        float4 l0 = lp[0], l1 = lp[1], l2 = lp[2], l3 = lp[3];
#pragma unroll 2
        for (int j = 0; j < 16; j++) {
            int hh = g3 + 16 * j;
            const float4* w14 = (const float4*)(W1 + hh * ND + c * 16);
            float a = dot4f(w14[0], l0) + dot4f(w14[1], l1) + dot4f(w14[2], l2) + dot4f(w14[3], l3);
            a += __shfl_xor(a, 1); a += __shfl_xor(a, 2); a += __shfl_xor(a, 4);
            if (c == 0) sh_gi[sl * NH + hh] = fmaxf(a + b1[hh], 0.f);
        }
        __syncthreads();
        const float4* hp = (const float4*)(sh_gi + sl * NH + c * 32);
        float4 h0 = hp[0], h1 = hp[1], h2 = hp[2], h3 = hp[3];
        float4 h4 = hp[4], h5 = hp[5], h6 = hp[6], h7 = hp[7];
#pragma unroll 2
        for (int j = 0; j < 8; j++) {
            int d = g3 + 16 * j;
            const float4* w24 = (const float4*)(W2 + d * NH + c * 32);
            float a = dot4f(w24[0], h0) + dot4f(w24[1], h1) + dot4f(w24[2], h2) + dot4f(w24[3], h3)
                    + dot4f(w24[4], h4) + dot4f(w24[5], h5) + dot4f(w24[6], h6) + dot4f(w24[7], h7);
            a += __shfl_xor(a, 1); a += __shfl_xor(a, 2); a += __shfl_xor(a, 4);
            if (c == 0) out[(size_t)b * NS * ND + (sh2 * 4 + sl) * ND + d] = a + b2[d] + sh_nr[sl * ND + d];
        }
    }
}

// ---------------------------------------------------------------------------
extern "C" void kernel_launch(void* const* d_in, const int* in_sizes, int n_in,
                              void* d_out, int out_size, void* d_ws, size_t ws_size,
                              hipStream_t stream) {
    (void)in_sizes; (void)n_in; (void)out_size; (void)ws_size;
    const float* inputs     = (const float*)d_in[0];
    const float* noise      = (const float*)d_in[1];
    const float* ln_in_w    = (const float*)d_in[2];
    const float* ln_in_b    = (const float*)d_in[3];
    const float* ln_s_w     = (const float*)d_in[4];
    const float* ln_s_b     = (const float*)d_in[5];
    const float* ln_m_w     = (const float*)d_in[6];
    const float* ln_m_b     = (const float*)d_in[7];
    const float* slot_mu    = (const float*)d_in[8];
    const float* slot_sigma = (const float*)d_in[9];
    const float* Wq         = (const float*)d_in[10];
    const float* Wk         = (const float*)d_in[11];
    const float* Wv         = (const float*)d_in[12];
    const float* W_ih       = (const float*)d_in[13];
    const float* W_hh       = (const float*)d_in[14];
    const float* b_ih       = (const float*)d_in[15];
    const float* b_hh       = (const float*)d_in[16];
    const float* W1         = (const float*)d_in[17];
    const float* b1         = (const float*)d_in[18];
    const float* W2         = (const float*)d_in[19];
    const float* b2         = (const float*)d_in[20];
    float* ws  = (float*)d_ws;
    float* out = (float*)d_out;

    hipLaunchKernelGGL(prep_kernel, dim3(288), dim3(256), 0, stream,
                       noise, ln_s_w, ln_s_b, slot_mu, slot_sigma, Wq, Wk, Wv, W_ih, ws);
    hipLaunchKernelGGL(qk0_kernel, dim3(NB), dim3(512), 0, stream, ws);
    for (int it = 0; it < 3; ++it) {
        hipLaunchKernelGGL(attn_kernel, dim3(NB * CHUNKS), dim3(256), 0, stream,
                           inputs, ln_in_w, ln_in_b, ws);
        if (it < 2) {
            hipLaunchKernelGGL((gru_kernel<0>), dim3(NB * 2), dim3(512), 0, stream,
                               W_hh, b_ih, b_hh, W1, b1, W2, b2, ln_m_w, ln_m_b, ws, out);
        } else {
            hipLaunchKernelGGL((gru_kernel<1>), dim3(NB * 2), dim3(512), 0, stream,
                               W_hh, b_ih, b_hh, W1, b1, W2, b2, ln_m_w, ln_m_b, ws, out);
        }
    }
}